// Round 1
// baseline (670.220 us; speedup 1.0000x reference)
//
#include <hip/hip_runtime.h>
#include <math.h>

// Problem constants (from reference)
constexpr int NN = 10000;      // nodes
constexpr int NE = 160000;     // edges (before self-loops)
constexpr int D_IN = 128, D_H1 = 512, D_H2 = 1024, D_H3 = 512, D_OUT = 32;

// ---------------------------------------------------------------------------
// Graph preprocessing
// ---------------------------------------------------------------------------

__global__ void zero_misc(int* degi, int* flag) {
    int i = blockIdx.x * blockDim.x + threadIdx.x;
    if (i < NN) degi[i] = 0;
    if (i == 0) *flag = 0;
}

// If edge_index is int64, every odd 32-bit word (high half) is 0 (values < 10000).
// If int32, odd words are random node ids — practically never all zero.
__global__ void detect_i64(const int* e, int* flag) {
    int i = blockIdx.x * blockDim.x + threadIdx.x;
    if (i < NE) {
        if (e[2 * i + 1] != 0) atomicOr(flag, 1);   // nonzero high word => int32 layout
    }
}

__global__ void convert_idx(const int* e, const int* flag, int* srcA, int* dstA) {
    int i = blockIdx.x * blockDim.x + threadIdx.x;
    if (i >= NE) return;
    if (*flag) {                   // int32 layout
        srcA[i] = e[i];
        dstA[i] = e[NE + i];
    } else {                       // int64 layout: take low words
        srcA[i] = e[2 * i];
        dstA[i] = e[2 * NE + 2 * i];
    }
}

__global__ void count_deg(const int* __restrict__ dstA, int* __restrict__ degi) {
    int i = blockIdx.x * blockDim.x + threadIdx.x;
    if (i < NE) atomicAdd(&degi[dstA[i]], 1);
}

__global__ void compute_dinv(const int* __restrict__ degi, float* __restrict__ dinv) {
    int i = blockIdx.x * blockDim.x + threadIdx.x;
    if (i < NN) dinv[i] = rsqrtf((float)(degi[i] + 1));  // +1 self-loop
}

// Single-block exclusive scan over NN counts -> rowptr, and fill = rowptr copy.
__global__ void scan_rowptr(const int* __restrict__ degi, int* __restrict__ rowptr,
                            int* __restrict__ fill) {
    __shared__ int sh[1024];
    __shared__ int carry_s;
    int tid = threadIdx.x;
    if (tid == 0) carry_s = 0;
    __syncthreads();
    for (int base = 0; base < NN; base += 1024) {
        int i = base + tid;
        int v = (i < NN) ? degi[i] : 0;
        sh[tid] = v;
        __syncthreads();
        for (int off = 1; off < 1024; off <<= 1) {
            int t = (tid >= off) ? sh[tid - off] : 0;
            __syncthreads();
            sh[tid] += t;
            __syncthreads();
        }
        int excl = sh[tid] - v + carry_s;
        if (i < NN) { rowptr[i] = excl; fill[i] = excl; }
        int total = sh[1023];
        __syncthreads();
        if (tid == 0) carry_s += total;
        __syncthreads();
    }
    if (tid == 0) rowptr[NN] = carry_s;
}

__global__ void scatter_edges(const int* __restrict__ srcA, const int* __restrict__ dstA,
                              int* __restrict__ fill, int* __restrict__ col) {
    int i = blockIdx.x * blockDim.x + threadIdx.x;
    if (i >= NE) return;
    int p = atomicAdd(&fill[dstA[i]], 1);
    col[p] = srcA[i];
}

// ---------------------------------------------------------------------------
// Pull aggregation: out[n,:] = dinv[n]^2 * in[n,:] + sum_e dinv[n]*dinv[src] * in[src,:]
// MODE 0: plain   MODE 1: +bias, relu   MODE 2: +bias
// One wave per (node, 64*VEC-dim chunk); vectorized gathers.
// ---------------------------------------------------------------------------
template <int VEC, int MODE>
__global__ __launch_bounds__(64) void agg_kernel(
    const float* __restrict__ in, float* __restrict__ out,
    const int* __restrict__ rowptr, const int* __restrict__ col,
    const float* __restrict__ dinv, const float* __restrict__ bias, int D) {
    int n = blockIdx.x;
    int lane = threadIdx.x;
    int d0 = (blockIdx.y * 64 + lane) * VEC;
    if (d0 >= D) return;
    float di = dinv[n];
    float acc[VEC];
    {
        float w = di * di;
        const float* r = in + (size_t)n * D + d0;
        if constexpr (VEC == 4) {
            float4 t = *reinterpret_cast<const float4*>(r);
            acc[0] = w * t.x; acc[1] = w * t.y; acc[2] = w * t.z; acc[3] = w * t.w;
        } else if constexpr (VEC == 2) {
            float2 t = *reinterpret_cast<const float2*>(r);
            acc[0] = w * t.x; acc[1] = w * t.y;
        } else {
            acc[0] = w * r[0];
        }
    }
    int e0 = rowptr[n], e1 = rowptr[n + 1];
    for (int e = e0; e < e1; ++e) {
        int s = col[e];
        float w = di * dinv[s];
        const float* r = in + (size_t)s * D + d0;
        if constexpr (VEC == 4) {
            float4 t = *reinterpret_cast<const float4*>(r);
            acc[0] = fmaf(w, t.x, acc[0]); acc[1] = fmaf(w, t.y, acc[1]);
            acc[2] = fmaf(w, t.z, acc[2]); acc[3] = fmaf(w, t.w, acc[3]);
        } else if constexpr (VEC == 2) {
            float2 t = *reinterpret_cast<const float2*>(r);
            acc[0] = fmaf(w, t.x, acc[0]); acc[1] = fmaf(w, t.y, acc[1]);
        } else {
            acc[0] = fmaf(w, r[0], acc[0]);
        }
    }
    float* o = out + (size_t)n * D + d0;
#pragma unroll
    for (int v = 0; v < VEC; ++v) {
        float x = acc[v];
        if (MODE >= 1) x += bias[d0 + v];
        if (MODE == 1) x = fmaxf(x, 0.0f);
        o[v] = x;
    }
}

// ---------------------------------------------------------------------------
// fp32 SGEMM: C[M,N] = A[M,K] @ B[K,N] (+bias, relu for MODE 1)
// 128x128 tile, BK=8, 256 threads, 8x8 microtile per thread.
// Requires K%8==0, N%128==0.
// ---------------------------------------------------------------------------
template <int MODE>
__global__ __launch_bounds__(256) void sgemm128(
    const float* __restrict__ A, const float* __restrict__ B,
    const float* __restrict__ bias, float* __restrict__ C,
    int M, int K, int N) {
    __shared__ float As[8][128];
    __shared__ float Bs[8][128];
    int tid = threadIdx.x;
    int bm = blockIdx.y, bn = blockIdx.x;
    int tx = tid & 15, ty = tid >> 4;
    int arow = tid >> 1, acol = (tid & 1) * 4;
    int brow = tid >> 5, bcol = (tid & 31) * 4;
    int gm = bm * 128 + arow;
    float acc[8][8] = {};
    const float* Aptr = A + (size_t)gm * K + acol;
    const float* Bptr = B + (size_t)brow * N + bn * 128 + bcol;

    for (int k0 = 0; k0 < K; k0 += 8) {
        float4 a;
        if (gm < M) a = *reinterpret_cast<const float4*>(Aptr + k0);
        else        a = float4{0.f, 0.f, 0.f, 0.f};
        float4 b = *reinterpret_cast<const float4*>(Bptr + (size_t)k0 * N);
        __syncthreads();
        As[acol + 0][arow] = a.x; As[acol + 1][arow] = a.y;
        As[acol + 2][arow] = a.z; As[acol + 3][arow] = a.w;
        *reinterpret_cast<float4*>(&Bs[brow][bcol]) = b;
        __syncthreads();
#pragma unroll
        for (int k = 0; k < 8; ++k) {
            float4 a0 = *reinterpret_cast<const float4*>(&As[k][ty * 8]);
            float4 a1 = *reinterpret_cast<const float4*>(&As[k][ty * 8 + 4]);
            float4 b0 = *reinterpret_cast<const float4*>(&Bs[k][tx * 8]);
            float4 b1 = *reinterpret_cast<const float4*>(&Bs[k][tx * 8 + 4]);
            float av[8] = {a0.x, a0.y, a0.z, a0.w, a1.x, a1.y, a1.z, a1.w};
            float bv[8] = {b0.x, b0.y, b0.z, b0.w, b1.x, b1.y, b1.z, b1.w};
#pragma unroll
            for (int i = 0; i < 8; ++i)
#pragma unroll
                for (int j = 0; j < 8; ++j)
                    acc[i][j] = fmaf(av[i], bv[j], acc[i][j]);
        }
    }

#pragma unroll
    for (int i = 0; i < 8; ++i) {
        int m = bm * 128 + ty * 8 + i;
        if (m >= M) continue;
        int ncol = bn * 128 + tx * 8;
        float vals[8];
#pragma unroll
        for (int j = 0; j < 8; ++j) {
            float x = acc[i][j];
            if (MODE == 1) { x += bias[ncol + j]; x = fmaxf(x, 0.f); }
            vals[j] = x;
        }
        float* dst = C + (size_t)m * N + ncol;
        *reinterpret_cast<float4*>(dst)     = float4{vals[0], vals[1], vals[2], vals[3]};
        *reinterpret_cast<float4*>(dst + 4) = float4{vals[4], vals[5], vals[6], vals[7]};
    }
}

// Small GEMM for W4: [NN,512] @ [512,32], no bias. One thread per output element.
__global__ void gemm_k512_n32(const float* __restrict__ A, const float* __restrict__ B,
                              float* __restrict__ C) {
    int idx = blockIdx.x * blockDim.x + threadIdx.x;
    int m = idx >> 5;
    int n = idx & 31;
    if (m >= NN) return;
    const float* a = A + (size_t)m * D_H3;
    float s = 0.f;
#pragma unroll 8
    for (int k = 0; k < D_H3; ++k) s = fmaf(a[k], B[k * 32 + n], s);
    C[(size_t)m * 32 + n] = s;
}

// In-place log_softmax over rows of 32.
__global__ void log_softmax32(float* __restrict__ out) {
    int gid = blockIdx.x * blockDim.x + threadIdx.x;
    int row = gid >> 5, lane = gid & 31;
    if (row >= NN) return;
    float v = out[row * 32 + lane];
    float mx = v;
#pragma unroll
    for (int o = 16; o; o >>= 1) mx = fmaxf(mx, __shfl_xor(mx, o));
    float e = expf(v - mx);
    float s = e;
#pragma unroll
    for (int o = 16; o; o >>= 1) s += __shfl_xor(s, o);
    out[row * 32 + lane] = v - mx - logf(s);
}

// ---------------------------------------------------------------------------

extern "C" void kernel_launch(void* const* d_in, const int* in_sizes, int n_in,
                              void* d_out, int out_size, void* d_ws, size_t ws_size,
                              hipStream_t stream) {
    const float* x  = (const float*)d_in[0];
    const int* eidx = (const int*)d_in[1];
    const float* W1 = (const float*)d_in[2]; const float* b1 = (const float*)d_in[3];
    const float* W2 = (const float*)d_in[4]; const float* b2 = (const float*)d_in[5];
    const float* W3 = (const float*)d_in[6]; const float* b3 = (const float*)d_in[7];
    const float* W4 = (const float*)d_in[8]; const float* b4 = (const float*)d_in[9];
    float* out = (float*)d_out;

    // workspace carve-up
    float* bufA  = (float*)d_ws;                       // NN*1024 floats
    float* bufB  = bufA + (size_t)NN * 1024;           // NN*1024 floats
    int* srcA    = (int*)(bufB + (size_t)NN * 1024);   // NE
    int* dstA    = srcA + NE;                          // NE
    int* col     = dstA + NE;                          // NE
    int* degi    = col + NE;                           // NN
    int* rowptr  = degi + NN;                          // NN+1
    int* fill    = rowptr + (NN + 1);                  // NN
    float* dinv  = (float*)(fill + NN);                // NN
    int* flag    = (int*)(dinv + NN);                  // 1

    const int B256 = 256;
    int gN = (NN + B256 - 1) / B256;
    int gE = (NE + B256 - 1) / B256;

    // --- graph preprocessing ---
    zero_misc<<<gN, B256, 0, stream>>>(degi, flag);
    detect_i64<<<gE, B256, 0, stream>>>(eidx, flag);
    convert_idx<<<gE, B256, 0, stream>>>(eidx, flag, srcA, dstA);
    count_deg<<<gE, B256, 0, stream>>>(dstA, degi);
    compute_dinv<<<gN, B256, 0, stream>>>(degi, dinv);
    scan_rowptr<<<1, 1024, 0, stream>>>(degi, rowptr, fill);
    scatter_edges<<<gE, B256, 0, stream>>>(srcA, dstA, fill, col);

    // --- layer 1: aggregate x (D=128), then GEMM+bias+relu ---
    agg_kernel<2, 0><<<dim3(NN, 1), 64, 0, stream>>>(x, bufA, rowptr, col, dinv, nullptr, D_IN);
    sgemm128<1><<<dim3(D_H1 / 128, (NN + 127) / 128), 256, 0, stream>>>(
        bufA, W1, b1, bufB, NN, D_IN, D_H1);

    // --- layer 2: aggregate h1 (D=512), then GEMM+bias+relu ---
    agg_kernel<4, 0><<<dim3(NN, 2), 64, 0, stream>>>(bufB, bufA, rowptr, col, dinv, nullptr, D_H1);
    sgemm128<1><<<dim3(D_H2 / 128, (NN + 127) / 128), 256, 0, stream>>>(
        bufA, W2, b2, bufB, NN, D_H1, D_H2);

    // --- layer 3: GEMM (no bias), then aggregate (D=512) + bias + relu ---
    sgemm128<0><<<dim3(D_H3 / 128, (NN + 127) / 128), 256, 0, stream>>>(
        bufB, W3, nullptr, bufA, NN, D_H2, D_H3);
    agg_kernel<4, 1><<<dim3(NN, 2), 64, 0, stream>>>(bufA, bufB, rowptr, col, dinv, b3, D_H3);

    // --- layer 4: small GEMM, aggregate (D=32) + bias, log_softmax ---
    gemm_k512_n32<<<(NN * 32 + B256 - 1) / B256, B256, 0, stream>>>(bufB, W4, bufA);
    agg_kernel<1, 2><<<dim3(NN, 1), 64, 0, stream>>>(bufA, out, rowptr, col, dinv, b4, D_OUT);
    log_softmax32<<<(NN * 32 + B256 - 1) / B256, B256, 0, stream>>>(out);
}

// Round 2
// 340.830 us; speedup vs baseline: 1.9664x; 1.9664x over previous
//
#include <hip/hip_runtime.h>
#include <math.h>

typedef _Float16 f16;
typedef f16 f16x8 __attribute__((ext_vector_type(8)));
typedef f16 f16x2 __attribute__((ext_vector_type(2)));
typedef float f32x4 __attribute__((ext_vector_type(4)));

constexpr int NN = 10000;      // nodes
constexpr int NE = 160000;     // edges (before self-loops)
constexpr int MPAD = 10112;    // 79 * 128, row padding for 128-tiles
constexpr int D_IN = 128, D_H1 = 512, D_H2 = 1024, D_H3 = 512, D_OUT = 32;

// ---------------------------------------------------------------------------
// Graph preprocessing (unchanged from round 1 — verified correct)
// ---------------------------------------------------------------------------

__global__ void zero_misc(int* degi, int* flag) {
    int i = blockIdx.x * blockDim.x + threadIdx.x;
    if (i < NN) degi[i] = 0;
    if (i == 0) *flag = 0;
}

__global__ void detect_i64(const int* e, int* flag) {
    int i = blockIdx.x * blockDim.x + threadIdx.x;
    if (i < NE) {
        if (e[2 * i + 1] != 0) atomicOr(flag, 1);   // nonzero high word => int32 layout
    }
}

__global__ void convert_idx(const int* e, const int* flag, int* srcA, int* dstA) {
    int i = blockIdx.x * blockDim.x + threadIdx.x;
    if (i >= NE) return;
    if (*flag) { srcA[i] = e[i];         dstA[i] = e[NE + i]; }
    else       { srcA[i] = e[2 * i];     dstA[i] = e[2 * NE + 2 * i]; }
}

__global__ void count_deg(const int* __restrict__ dstA, int* __restrict__ degi) {
    int i = blockIdx.x * blockDim.x + threadIdx.x;
    if (i < NE) atomicAdd(&degi[dstA[i]], 1);
}

__global__ void compute_dinv(const int* __restrict__ degi, float* __restrict__ dinv) {
    int i = blockIdx.x * blockDim.x + threadIdx.x;
    if (i < NN) dinv[i] = rsqrtf((float)(degi[i] + 1));  // +1 self-loop
}

__global__ void scan_rowptr(const int* __restrict__ degi, int* __restrict__ rowptr,
                            int* __restrict__ fill) {
    __shared__ int sh[1024];
    __shared__ int carry_s;
    int tid = threadIdx.x;
    if (tid == 0) carry_s = 0;
    __syncthreads();
    for (int base = 0; base < NN; base += 1024) {
        int i = base + tid;
        int v = (i < NN) ? degi[i] : 0;
        sh[tid] = v;
        __syncthreads();
        for (int off = 1; off < 1024; off <<= 1) {
            int t = (tid >= off) ? sh[tid - off] : 0;
            __syncthreads();
            sh[tid] += t;
            __syncthreads();
        }
        int excl = sh[tid] - v + carry_s;
        if (i < NN) { rowptr[i] = excl; fill[i] = excl; }
        int total = sh[1023];
        __syncthreads();
        if (tid == 0) carry_s += total;
        __syncthreads();
    }
    if (tid == 0) rowptr[NN] = carry_s;
}

__global__ void scatter_edges(const int* __restrict__ srcA, const int* __restrict__ dstA,
                              int* __restrict__ fill, int* __restrict__ col) {
    int i = blockIdx.x * blockDim.x + threadIdx.x;
    if (i >= NE) return;
    int p = atomicAdd(&fill[dstA[i]], 1);
    col[p] = srcA[i];
}

// Weight prep: W[K][N] fp32 -> Wt[N][K] fp16 (transposed, K-contiguous for MFMA)
__global__ void prep_wt(const float* __restrict__ W, f16* __restrict__ Wt, int K, int N) {
    int idx = blockIdx.x * blockDim.x + threadIdx.x;
    if (idx >= K * N) return;
    int k = idx / N, n = idx - k * N;
    Wt[(size_t)n * K + k] = (f16)W[idx];
}

// ---------------------------------------------------------------------------
// Pull aggregation, dtype-templated.
// out[n,:] = dinv[n]^2*in[n,:] + sum_e dinv[n]*dinv[src]*in[src,:]
// MODE 0: plain   MODE 1: +bias, relu   MODE 2: +bias
// One wave per node; VEC elements per lane (D <= 64*VEC).
// ---------------------------------------------------------------------------
template <typename TIN, int VEC>
__device__ __forceinline__ void acc_row(const TIN* p, float w, float (&a)[VEC]) {
    if constexpr (sizeof(TIN) == 2) {
        static_assert(VEC == 8, "fp16 path uses VEC=8");
        f16x8 t = *reinterpret_cast<const f16x8*>(p);
#pragma unroll
        for (int j = 0; j < 8; ++j) a[j] = fmaf(w, (float)t[j], a[j]);
    } else if constexpr (VEC == 2) {
        float2 t = *reinterpret_cast<const float2*>(p);
        a[0] = fmaf(w, t.x, a[0]); a[1] = fmaf(w, t.y, a[1]);
    } else {
        a[0] = fmaf(w, p[0], a[0]);
    }
}

template <typename TIN, typename TOUT, int VEC, int MODE>
__global__ __launch_bounds__(64) void agg_kernel(
    const TIN* __restrict__ in, TOUT* __restrict__ out,
    const int* __restrict__ rowptr, const int* __restrict__ col,
    const float* __restrict__ dinv, const float* __restrict__ bias, int D) {
    int n = blockIdx.x;
    int lane = threadIdx.x;
    int d0 = lane * VEC;
    if (d0 >= D) return;
    float di = dinv[n];
    float acc[VEC];
#pragma unroll
    for (int v = 0; v < VEC; ++v) acc[v] = 0.f;
    acc_row<TIN, VEC>(in + (size_t)n * D + d0, di * di, acc);
    int e0 = rowptr[n], e1 = rowptr[n + 1];
    for (int e = e0; e < e1; ++e) {
        int s = col[e];
        acc_row<TIN, VEC>(in + (size_t)s * D + d0, di * dinv[s], acc);
    }
#pragma unroll
    for (int v = 0; v < VEC; ++v) {
        if (MODE >= 1) acc[v] += bias[d0 + v];
        if (MODE == 1) acc[v] = fmaxf(acc[v], 0.f);
    }
    if constexpr (sizeof(TOUT) == 2) {
        if constexpr (VEC == 8) {
            f16x8 o;
#pragma unroll
            for (int v = 0; v < 8; ++v) o[v] = (f16)acc[v];
            *reinterpret_cast<f16x8*>(out + (size_t)n * D + d0) = o;
        } else {  // VEC == 2
            f16x2 o; o[0] = (f16)acc[0]; o[1] = (f16)acc[1];
            *reinterpret_cast<f16x2*>(out + (size_t)n * D + d0) = o;
        }
    } else {
        TOUT* o = out + (size_t)n * D + d0;
#pragma unroll
        for (int v = 0; v < VEC; ++v) o[v] = acc[v];
    }
}

// ---------------------------------------------------------------------------
// fp16 MFMA GEMM: C[M,N] = A[M,K] @ Bt[N,K]^T, fp32 accumulate, fp16 out.
// 128x128 tile, BK=32, 256 threads = 4 waves (2x2), 64x64 per wave,
// mfma_f32_16x16x32_f16 in 4x4 fragments. Requires M % 128 == 0 (padded),
// N % 128 == 0, K % 32 == 0.
// LDS: linear dest for global_load_lds; 16B-slot XOR swizzle applied on the
// GLOBAL source and on the ds_read side (same involution), per rule 21.
// MODE 0: plain   MODE 1: +bias, relu
// ---------------------------------------------------------------------------
__device__ __forceinline__ void gload_lds16(const void* g, void* lds) {
    __builtin_amdgcn_global_load_lds(
        (const __attribute__((address_space(1))) void*)g,
        (__attribute__((address_space(3))) void*)lds, 16, 0, 0);
}

template <int MODE>
__global__ __launch_bounds__(256) void hgemm(
    const f16* __restrict__ A, const f16* __restrict__ Bt,
    const float* __restrict__ bias, f16* __restrict__ C, int K, int N) {
    __shared__ __align__(16) f16 As[128 * 32];
    __shared__ __align__(16) f16 Bs[128 * 32];
    const int tid = threadIdx.x;
    const int lane = tid & 63, w = tid >> 6;
    const int wm = w >> 1, wn = w & 1;
    const int bn = blockIdx.x, bm = blockIdx.y;

    f32x4 acc[4][4] = {};

    // staging decomposition: thread t owns LDS bytes [t*16 + i*4096)
    const int srow = tid >> 2;     // row (0..63), +64 for i=1
    const int sslot = tid & 3;     // 16B slot within 64B row

    for (int k0 = 0; k0 < K; k0 += 32) {
        if (k0) __syncthreads();   // prev tile fully consumed
#pragma unroll
        for (int i = 0; i < 2; ++i) {
            int row = srow + i * 64;
            int g = sslot ^ ((row >> 1) & 3);          // inverse-swizzled source slot
            gload_lds16(A + (size_t)(bm * 128 + row) * K + k0 + g * 8,
                        (char*)As + w * 1024 + i * 4096);
            gload_lds16(Bt + (size_t)(bn * 128 + row) * K + k0 + g * 8,
                        (char*)Bs + w * 1024 + i * 4096);
        }
        __syncthreads();           // compiler drains vmcnt before barrier

        f16x8 af[4], bf[4];
        const int kg = lane >> 4;
#pragma unroll
        for (int m = 0; m < 4; ++m) {
            int row = wm * 64 + m * 16 + (lane & 15);
            int s = kg ^ ((row >> 1) & 3);
            af[m] = *reinterpret_cast<const f16x8*>((const char*)As + row * 64 + s * 16);
        }
#pragma unroll
        for (int n = 0; n < 4; ++n) {
            int row = wn * 64 + n * 16 + (lane & 15);
            int s = kg ^ ((row >> 1) & 3);
            bf[n] = *reinterpret_cast<const f16x8*>((const char*)Bs + row * 64 + s * 16);
        }
#pragma unroll
        for (int m = 0; m < 4; ++m)
#pragma unroll
            for (int n = 0; n < 4; ++n)
                acc[m][n] = __builtin_amdgcn_mfma_f32_16x16x32_f16(af[m], bf[n], acc[m][n], 0, 0, 0);
    }

    // epilogue: C row = (lane>>4)*4 + reg, col = lane&15 (m89-verified mapping)
#pragma unroll
    for (int n = 0; n < 4; ++n) {
        int colg = bn * 128 + wn * 64 + n * 16 + (lane & 15);
        float bv = (MODE == 1) ? bias[colg] : 0.f;
#pragma unroll
        for (int m = 0; m < 4; ++m) {
            int rbase = bm * 128 + wm * 64 + m * 16 + ((lane >> 4) << 2);
#pragma unroll
            for (int r = 0; r < 4; ++r) {
                float x = acc[m][n][r];
                if (MODE == 1) { x += bv; x = fmaxf(x, 0.f); }
                C[(size_t)(rbase + r) * N + colg] = (f16)x;
            }
        }
    }
}

// Small GEMM for W4: [NN,512] @ [512,32] fp32, no bias.
__global__ void gemm_k512_n32(const float* __restrict__ A, const float* __restrict__ B,
                              float* __restrict__ C) {
    int idx = blockIdx.x * blockDim.x + threadIdx.x;
    int m = idx >> 5;
    int n = idx & 31;
    if (m >= NN) return;
    const float* a = A + (size_t)m * D_H3;
    float s = 0.f;
#pragma unroll 8
    for (int k = 0; k < D_H3; ++k) s = fmaf(a[k], B[k * 32 + n], s);
    C[(size_t)m * 32 + n] = s;
}

// In-place log_softmax over rows of 32.
__global__ void log_softmax32(float* __restrict__ out) {
    int gid = blockIdx.x * blockDim.x + threadIdx.x;
    int row = gid >> 5, lane = gid & 31;
    if (row >= NN) return;
    float v = out[row * 32 + lane];
    float mx = v;
#pragma unroll
    for (int o = 16; o; o >>= 1) mx = fmaxf(mx, __shfl_xor(mx, o));
    float e = expf(v - mx);
    float s = e;
#pragma unroll
    for (int o = 16; o; o >>= 1) s += __shfl_xor(s, o);
    out[row * 32 + lane] = v - mx - logf(s);
}

// ---------------------------------------------------------------------------

extern "C" void kernel_launch(void* const* d_in, const int* in_sizes, int n_in,
                              void* d_out, int out_size, void* d_ws, size_t ws_size,
                              hipStream_t stream) {
    const float* x  = (const float*)d_in[0];
    const int* eidx = (const int*)d_in[1];
    const float* W1 = (const float*)d_in[2]; const float* b1 = (const float*)d_in[3];
    const float* W2 = (const float*)d_in[4]; const float* b2 = (const float*)d_in[5];
    const float* W3 = (const float*)d_in[6]; const float* b3 = (const float*)d_in[7];
    const float* W4 = (const float*)d_in[8]; const float* b4 = (const float*)d_in[9];
    float* out = (float*)d_out;

    // workspace carve-up (~67.6 MB total; round-1 layout used ~84 MB OK)
    f16* P1    = (f16*)d_ws;                           // [MPAD][<=1024] fp16, 20.7 MB
    f16* P2    = P1 + (size_t)MPAD * 1024;             // [MPAD][<=1024] fp16, 20.7 MB
    float* fA3 = (float*)(P2 + (size_t)MPAD * 1024);   // [NN][512] fp32, 20.5 MB
    float* g4o = fA3 + (size_t)NN * 512;               // [NN][32] fp32
    f16* Wt1   = (f16*)(g4o + (size_t)NN * 32);        // [512][128]
    f16* Wt2   = Wt1 + 512 * 128;                      // [1024][512]
    f16* Wt3   = Wt2 + 1024 * 512;                     // [512][1024]
    int* srcA  = (int*)(Wt3 + 512 * 1024);             // NE
    int* dstA  = srcA + NE;
    int* colA  = dstA + NE;
    int* degi  = colA + NE;
    int* rowptr = degi + NN;                           // NN+1
    int* fill  = rowptr + (NN + 1);
    float* dinv = (float*)(fill + NN);
    int* flag  = (int*)(dinv + NN);

    const int B256 = 256;
    int gN = (NN + B256 - 1) / B256;
    int gE = (NE + B256 - 1) / B256;

    // --- graph + weight preprocessing ---
    zero_misc<<<gN, B256, 0, stream>>>(degi, flag);
    detect_i64<<<gE, B256, 0, stream>>>(eidx, flag);
    convert_idx<<<gE, B256, 0, stream>>>(eidx, flag, srcA, dstA);
    count_deg<<<gE, B256, 0, stream>>>(dstA, degi);
    compute_dinv<<<gN, B256, 0, stream>>>(degi, dinv);
    scan_rowptr<<<1, 1024, 0, stream>>>(degi, rowptr, fill);
    scatter_edges<<<gE, B256, 0, stream>>>(srcA, dstA, fill, colA);
    prep_wt<<<(D_IN * D_H1 + 255) / 256, B256, 0, stream>>>(W1, Wt1, D_IN, D_H1);
    prep_wt<<<(D_H1 * D_H2 + 255) / 256, B256, 0, stream>>>(W2, Wt2, D_H1, D_H2);
    prep_wt<<<(D_H2 * D_H3 + 255) / 256, B256, 0, stream>>>(W3, Wt3, D_H2, D_H3);

    // --- layer 1: aggregate x (fp32 in, fp16 out), GEMM1 + bias + relu ---
    agg_kernel<float, f16, 2, 0><<<NN, 64, 0, stream>>>(x, P1, rowptr, colA, dinv, nullptr, D_IN);
    hgemm<1><<<dim3(D_H1 / 128, MPAD / 128), 256, 0, stream>>>(P1, Wt1, b1, P2, D_IN, D_H1);

    // --- layer 2: aggregate h1 (fp16), GEMM2 + bias + relu ---
    agg_kernel<f16, f16, 8, 0><<<NN, 64, 0, stream>>>(P2, P1, rowptr, colA, dinv, nullptr, D_H1);
    hgemm<1><<<dim3(D_H2 / 128, MPAD / 128), 256, 0, stream>>>(P1, Wt2, b2, P2, D_H1, D_H2);

    // --- layer 3: GEMM3 (plain), aggregate + bias + relu (fp32 out) ---
    hgemm<0><<<dim3(D_H3 / 128, MPAD / 128), 256, 0, stream>>>(P2, Wt3, nullptr, P1, D_H2, D_H3);
    agg_kernel<f16, float, 8, 1><<<NN, 64, 0, stream>>>(P1, fA3, rowptr, colA, dinv, b3, D_H3);

    // --- layer 4: small GEMM, aggregate (D=32) + bias, log_softmax ---
    gemm_k512_n32<<<(NN * 32 + B256 - 1) / B256, B256, 0, stream>>>(fA3, W4, g4o);
    agg_kernel<float, float, 1, 2><<<NN, 64, 0, stream>>>(g4o, out, rowptr, colA, dinv, b4, D_OUT);
    log_softmax32<<<(NN * 32 + B256 - 1) / B256, B256, 0, stream>>>(out);
}

// Round 3
// 304.087 us; speedup vs baseline: 2.2040x; 1.1208x over previous
//
#include <hip/hip_runtime.h>
#include <math.h>

typedef _Float16 f16;
typedef f16 f16x8 __attribute__((ext_vector_type(8)));
typedef f16 f16x2 __attribute__((ext_vector_type(2)));
typedef float f32x4 __attribute__((ext_vector_type(4)));

constexpr int NN = 10000;      // nodes
constexpr int NE = 160000;     // edges (before self-loops)
constexpr int MPAD = 10112;    // 79 * 128, row padding for 128-tiles
constexpr int D_IN = 128, D_H1 = 512, D_H2 = 1024, D_H3 = 512, D_OUT = 32;

// ---------------------------------------------------------------------------
// Graph preprocessing
// ---------------------------------------------------------------------------

__global__ void zero_misc(int* degi_flag) {     // degi[NN] + flag[1], contiguous
    int i = blockIdx.x * blockDim.x + threadIdx.x;
    if (i < NN + 1) degi_flag[i] = 0;
}

// int64 edge_index => odd 32-bit words (high halves) all zero (ids < 10000).
__global__ void detect_i64(const int* e, int* flag) {
    int i = blockIdx.x * blockDim.x + threadIdx.x;
    if (i < NE) {
        if (e[2 * i + 1] != 0) atomicOr(flag, 1);   // nonzero high word => int32 layout
    }
}

__global__ void convert_count(const int* __restrict__ e, const int* __restrict__ flag,
                              int* __restrict__ srcA, int* __restrict__ dstA,
                              int* __restrict__ degi) {
    int i = blockIdx.x * blockDim.x + threadIdx.x;
    if (i >= NE) return;
    int s, d;
    if (*flag) { s = e[i];     d = e[NE + i]; }
    else       { s = e[2 * i]; d = e[2 * NE + 2 * i]; }
    srcA[i] = s; dstA[i] = d;
    atomicAdd(&degi[d], 1);
}

// Single-block scan: degi -> rowptr (exclusive) + fill copy + dinv.
__global__ void scan_rowptr(const int* __restrict__ degi, int* __restrict__ rowptr,
                            int* __restrict__ fill, float* __restrict__ dinv) {
    __shared__ int sh[1024];
    __shared__ int carry_s;
    int tid = threadIdx.x;
    if (tid == 0) carry_s = 0;
    __syncthreads();
    for (int base = 0; base < NN; base += 1024) {
        int i = base + tid;
        int v = (i < NN) ? degi[i] : 0;
        if (i < NN) dinv[i] = rsqrtf((float)(v + 1));  // +1 self-loop
        sh[tid] = v;
        __syncthreads();
        for (int off = 1; off < 1024; off <<= 1) {
            int t = (tid >= off) ? sh[tid - off] : 0;
            __syncthreads();
            sh[tid] += t;
            __syncthreads();
        }
        int excl = sh[tid] - v + carry_s;
        if (i < NN) { rowptr[i] = excl; fill[i] = excl; }
        int total = sh[1023];
        __syncthreads();
        if (tid == 0) carry_s += total;
        __syncthreads();
    }
    if (tid == 0) rowptr[NN] = carry_s;
}

__global__ void scatter_edges(const int* __restrict__ srcA, const int* __restrict__ dstA,
                              int* __restrict__ fill, int* __restrict__ col) {
    int i = blockIdx.x * blockDim.x + threadIdx.x;
    if (i >= NE) return;
    int p = atomicAdd(&fill[dstA[i]], 1);
    col[p] = srcA[i];
}

// All weight preps in one kernel: W[K][N] fp32 -> Wt[N][K] fp16 (K-contiguous).
// Wt4 is N-padded to 128 rows (zeros beyond 32).
__global__ void prep_all(const float* __restrict__ W1, const float* __restrict__ W2,
                         const float* __restrict__ W3, const float* __restrict__ W4,
                         f16* __restrict__ Wt1, f16* __restrict__ Wt2,
                         f16* __restrict__ Wt3, f16* __restrict__ Wt4) {
    int idx = blockIdx.x * blockDim.x + threadIdx.x;
    if (idx < 512 * 128) {               // Wt1 [512][128] <- W1 [128][512]
        int n = idx >> 7, k = idx & 127;
        Wt1[idx] = (f16)W1[k * 512 + n];
        return;
    }
    idx -= 512 * 128;
    if (idx < 1024 * 512) {              // Wt2 [1024][512] <- W2 [512][1024]
        int n = idx >> 9, k = idx & 511;
        Wt2[idx] = (f16)W2[k * 1024 + n];
        return;
    }
    idx -= 1024 * 512;
    if (idx < 512 * 1024) {              // Wt3 [512][1024] <- W3 [1024][512]
        int n = idx >> 10, k = idx & 1023;
        Wt3[idx] = (f16)W3[k * 512 + n];
        return;
    }
    idx -= 512 * 1024;
    if (idx < 128 * 512) {               // Wt4 [128][512] <- W4 [512][32], zero-padded
        int n = idx >> 9, k = idx & 511;
        Wt4[idx] = (n < 32) ? (f16)W4[k * 32 + n] : (f16)0.f;
        return;
    }
}

// ---------------------------------------------------------------------------
// Pull aggregation, dtype-templated.
// out[n,:] = dinv[n]^2*in[n,:] + sum_e dinv[n]*dinv[src]*in[src,:]
// MODE 0: plain   MODE 1: +bias, relu
// One wave per node; VEC elements per lane (D <= 64*VEC).
// ---------------------------------------------------------------------------
template <typename TIN, int VEC>
__device__ __forceinline__ void acc_row(const TIN* p, float w, float (&a)[VEC]) {
    if constexpr (sizeof(TIN) == 2) {
        static_assert(VEC == 8, "fp16 path uses VEC=8");
        f16x8 t = *reinterpret_cast<const f16x8*>(p);
#pragma unroll
        for (int j = 0; j < 8; ++j) a[j] = fmaf(w, (float)t[j], a[j]);
    } else if constexpr (VEC == 2) {
        float2 t = *reinterpret_cast<const float2*>(p);
        a[0] = fmaf(w, t.x, a[0]); a[1] = fmaf(w, t.y, a[1]);
    } else {
        a[0] = fmaf(w, p[0], a[0]);
    }
}

template <typename TIN, typename TOUT, int VEC, int MODE>
__global__ __launch_bounds__(64) void agg_kernel(
    const TIN* __restrict__ in, TOUT* __restrict__ out,
    const int* __restrict__ rowptr, const int* __restrict__ col,
    const float* __restrict__ dinv, const float* __restrict__ bias, int D) {
    int n = blockIdx.x;
    int lane = threadIdx.x;
    int d0 = lane * VEC;
    if (d0 >= D) return;
    float di = dinv[n];
    float acc[VEC];
#pragma unroll
    for (int v = 0; v < VEC; ++v) acc[v] = 0.f;
    acc_row<TIN, VEC>(in + (size_t)n * D + d0, di * di, acc);
    int e0 = rowptr[n], e1 = rowptr[n + 1];
    for (int e = e0; e < e1; ++e) {
        int s = col[e];
        acc_row<TIN, VEC>(in + (size_t)s * D + d0, di * dinv[s], acc);
    }
#pragma unroll
    for (int v = 0; v < VEC; ++v) {
        if (MODE >= 1) acc[v] += bias[d0 + v];
        if (MODE == 1) acc[v] = fmaxf(acc[v], 0.f);
    }
    if constexpr (sizeof(TOUT) == 2) {
        if constexpr (VEC == 8) {
            f16x8 o;
#pragma unroll
            for (int v = 0; v < 8; ++v) o[v] = (f16)acc[v];
            *reinterpret_cast<f16x8*>(out + (size_t)n * D + d0) = o;
        } else {  // VEC == 2
            f16x2 o; o[0] = (f16)acc[0]; o[1] = (f16)acc[1];
            *reinterpret_cast<f16x2*>(out + (size_t)n * D + d0) = o;
        }
    } else {
        TOUT* o = out + (size_t)n * D + d0;
#pragma unroll
        for (int v = 0; v < VEC; ++v) o[v] = acc[v];
    }
}

// ---------------------------------------------------------------------------
// fp16 MFMA GEMM: C[M,N] = A[M,K] @ Bt[N,K]^T, fp32 accumulate, fp16 out.
// 128x128 tile, BK=32, 256 threads = 4 waves (2x2), 64x64 per wave,
// mfma_f32_16x16x32_f16 in 4x4 fragments. M % 128 == 0 (padded), N % 128 == 0,
// K % 32 == 0. LDS: linear dest for global_load_lds; 16B-slot XOR swizzle on
// the GLOBAL source and the ds_read side (same involution), per rule 21.
// MODE 0: plain   MODE 1: +bias, relu
// ---------------------------------------------------------------------------
__device__ __forceinline__ void gload_lds16(const void* g, void* lds) {
    __builtin_amdgcn_global_load_lds(
        (const __attribute__((address_space(1))) void*)g,
        (__attribute__((address_space(3))) void*)lds, 16, 0, 0);
}

template <int MODE>
__global__ __launch_bounds__(256) void hgemm(
    const f16* __restrict__ A, const f16* __restrict__ Bt,
    const float* __restrict__ bias, f16* __restrict__ C, int K, int N) {
    __shared__ __align__(16) f16 As[128 * 32];
    __shared__ __align__(16) f16 Bs[128 * 32];
    const int tid = threadIdx.x;
    const int lane = tid & 63, w = tid >> 6;
    const int wm = w >> 1, wn = w & 1;
    const int bn = blockIdx.x, bm = blockIdx.y;

    f32x4 acc[4][4] = {};

    const int srow = tid >> 2;     // staging row (0..63), +64 for i=1
    const int sslot = tid & 3;     // 16B slot within 64B row

    for (int k0 = 0; k0 < K; k0 += 32) {
        if (k0) __syncthreads();
#pragma unroll
        for (int i = 0; i < 2; ++i) {
            int row = srow + i * 64;
            int g = sslot ^ ((row >> 1) & 3);          // inverse-swizzled source slot
            gload_lds16(A + (size_t)(bm * 128 + row) * K + k0 + g * 8,
                        (char*)As + w * 1024 + i * 4096);
            gload_lds16(Bt + (size_t)(bn * 128 + row) * K + k0 + g * 8,
                        (char*)Bs + w * 1024 + i * 4096);
        }
        __syncthreads();

        f16x8 af[4], bf[4];
        const int kg = lane >> 4;
#pragma unroll
        for (int m = 0; m < 4; ++m) {
            int row = wm * 64 + m * 16 + (lane & 15);
            int s = kg ^ ((row >> 1) & 3);
            af[m] = *reinterpret_cast<const f16x8*>((const char*)As + row * 64 + s * 16);
        }
#pragma unroll
        for (int n = 0; n < 4; ++n) {
            int row = wn * 64 + n * 16 + (lane & 15);
            int s = kg ^ ((row >> 1) & 3);
            bf[n] = *reinterpret_cast<const f16x8*>((const char*)Bs + row * 64 + s * 16);
        }
#pragma unroll
        for (int m = 0; m < 4; ++m)
#pragma unroll
            for (int n = 0; n < 4; ++n)
                acc[m][n] = __builtin_amdgcn_mfma_f32_16x16x32_f16(af[m], bf[n], acc[m][n], 0, 0, 0);
    }

    // epilogue: C row = (lane>>4)*4 + reg, col = lane&15 (m89-verified mapping)
#pragma unroll
    for (int n = 0; n < 4; ++n) {
        int colg = bn * 128 + wn * 64 + n * 16 + (lane & 15);
        float bv = (MODE == 1) ? bias[colg] : 0.f;
#pragma unroll
        for (int m = 0; m < 4; ++m) {
            int rbase = bm * 128 + wm * 64 + m * 16 + ((lane >> 4) << 2);
#pragma unroll
            for (int r = 0; r < 4; ++r) {
                float x = acc[m][n][r];
                if (MODE == 1) { x += bv; x = fmaxf(x, 0.f); }
                C[(size_t)(rbase + r) * N + colg] = (f16)x;
            }
        }
    }
}

// ---------------------------------------------------------------------------
// Final: aggregate logits (D=32, stride 128) + bias + log_softmax, fused.
// 2 nodes per wave; lanes 0..31 = node A cols, lanes 32..63 = node B cols.
// ---------------------------------------------------------------------------
__global__ __launch_bounds__(64) void final_agg_softmax(
    const f16* __restrict__ in,     // [MPAD][128], cols 0..31 valid
    float* __restrict__ out,        // [NN][32]
    const int* __restrict__ rowptr, const int* __restrict__ col,
    const float* __restrict__ dinv, const float* __restrict__ b4) {
    int n = blockIdx.x * 2 + (threadIdx.x >> 5);
    int c = threadIdx.x & 31;
    if (n >= NN) return;
    float di = dinv[n];
    float acc = di * di * (float)in[(size_t)n * 128 + c];
    int e0 = rowptr[n], e1 = rowptr[n + 1];
    for (int e = e0; e < e1; ++e) {
        int s = col[e];
        acc = fmaf(di * dinv[s], (float)in[(size_t)s * 128 + c], acc);
    }
    float v = acc + b4[c];
    float mx = v;
#pragma unroll
    for (int o = 16; o; o >>= 1) mx = fmaxf(mx, __shfl_xor(mx, o, 32));
    float e = expf(v - mx);
    float s = e;
#pragma unroll
    for (int o = 16; o; o >>= 1) s += __shfl_xor(s, o, 32);
    out[(size_t)n * 32 + c] = v - mx - logf(s);
}

// ---------------------------------------------------------------------------

extern "C" void kernel_launch(void* const* d_in, const int* in_sizes, int n_in,
                              void* d_out, int out_size, void* d_ws, size_t ws_size,
                              hipStream_t stream) {
    const float* x  = (const float*)d_in[0];
    const int* eidx = (const int*)d_in[1];
    const float* W1 = (const float*)d_in[2]; const float* b1 = (const float*)d_in[3];
    const float* W2 = (const float*)d_in[4]; const float* b2 = (const float*)d_in[5];
    const float* W3 = (const float*)d_in[6]; const float* b3 = (const float*)d_in[7];
    const float* W4 = (const float*)d_in[8]; const float* b4 = (const float*)d_in[9];
    float* out = (float*)d_out;

    // workspace carve-up (~46 MB)
    f16* P1    = (f16*)d_ws;                           // [MPAD][<=1024]
    f16* P2    = P1 + (size_t)MPAD * 1024;             // [MPAD][<=1024]
    f16* Wt1   = P2 + (size_t)MPAD * 1024;             // [512][128]
    f16* Wt2   = Wt1 + 512 * 128;                      // [1024][512]
    f16* Wt3   = Wt2 + 1024 * 512;                     // [512][1024]
    f16* Wt4   = Wt3 + 512 * 1024;                     // [128][512] (zero-padded)
    int* srcA  = (int*)(Wt4 + 128 * 512);              // NE
    int* dstA  = srcA + NE;
    int* colA  = dstA + NE;
    int* degi  = colA + NE;                            // NN (+flag right after)
    int* flag  = degi + NN;                            // 1
    int* rowptr = flag + 1;                            // NN+1
    int* fill  = rowptr + (NN + 1);                    // NN
    float* dinv = (float*)(fill + NN);                 // NN

    const int B256 = 256;
    int gE = (NE + B256 - 1) / B256;

    // --- graph + weight preprocessing (7 dispatches) ---
    zero_misc<<<(NN + 1 + B256 - 1) / B256, B256, 0, stream>>>(degi);
    detect_i64<<<gE, B256, 0, stream>>>(eidx, flag);
    convert_count<<<gE, B256, 0, stream>>>(eidx, flag, srcA, dstA, degi);
    scan_rowptr<<<1, 1024, 0, stream>>>(degi, rowptr, fill, dinv);
    scatter_edges<<<gE, B256, 0, stream>>>(srcA, dstA, fill, colA);
    prep_all<<<(512 * 128 + 1024 * 512 + 512 * 1024 + 128 * 512 + 255) / 256, B256, 0, stream>>>(
        W1, W2, W3, W4, Wt1, Wt2, Wt3, Wt4);

    // --- layer 1: aggregate x (fp32 in, fp16 out), GEMM1 + bias + relu ---
    agg_kernel<float, f16, 2, 0><<<NN, 64, 0, stream>>>(x, P1, rowptr, colA, dinv, nullptr, D_IN);
    hgemm<1><<<dim3(D_H1 / 128, MPAD / 128), 256, 0, stream>>>(P1, Wt1, b1, P2, D_IN, D_H1);

    // --- layer 2: aggregate h1 (fp16), GEMM2 + bias + relu ---
    agg_kernel<f16, f16, 8, 0><<<NN, 64, 0, stream>>>(P2, P1, rowptr, colA, dinv, nullptr, D_H1);
    hgemm<1><<<dim3(D_H2 / 128, MPAD / 128), 256, 0, stream>>>(P1, Wt2, b2, P2, D_H1, D_H2);

    // --- layer 3: GEMM3 (plain), aggregate + bias + relu (fp16 out) ---
    hgemm<0><<<dim3(D_H3 / 128, MPAD / 128), 256, 0, stream>>>(P2, Wt3, nullptr, P1, D_H2, D_H3);
    agg_kernel<f16, f16, 8, 1><<<NN, 64, 0, stream>>>(P1, P2, rowptr, colA, dinv, b3, D_H3);

    // --- layer 4: MFMA GEMM on zero-padded W4 (N=128), fused agg+softmax ---
    hgemm<0><<<dim3(1, MPAD / 128), 256, 0, stream>>>(P2, Wt4, nullptr, P1, D_H3, 128);
    final_agg_softmax<<<NN / 2, 64, 0, stream>>>(P1, out, rowptr, colA, dinv, b4);
}

// Round 5
// 286.006 us; speedup vs baseline: 2.3434x; 1.0632x over previous
//
#include <hip/hip_runtime.h>
#include <math.h>

typedef _Float16 f16;
typedef f16 f16x8 __attribute__((ext_vector_type(8)));
typedef f16 f16x2 __attribute__((ext_vector_type(2)));
typedef float f32x4 __attribute__((ext_vector_type(4)));

constexpr int NN = 10000;      // nodes
constexpr int NE = 160000;     // edges (before self-loops)
constexpr int MPAD = 10112;    // 79 * 128, row padding for 128-tiles
constexpr int D_IN = 128, D_H1 = 512, D_H2 = 1024, D_H3 = 512, D_OUT = 32;

// ---------------------------------------------------------------------------
// Kernel 1: all one-shot prep — zero degi+flag, convert weights (transposed
// fp16, K-contiguous), convert x to fp16. No inter-dependencies.
// ---------------------------------------------------------------------------
__global__ void prep_all(const float* __restrict__ W1, const float* __restrict__ W2,
                         const float* __restrict__ W3, const float* __restrict__ W4,
                         const float* __restrict__ x,
                         f16* __restrict__ Wt1, f16* __restrict__ Wt2,
                         f16* __restrict__ Wt3, f16* __restrict__ Wt4,
                         f16* __restrict__ xh, int* __restrict__ degi_flag) {
    int idx = blockIdx.x * blockDim.x + threadIdx.x;
    if (idx < 512 * 128) {               // Wt1 [512][128] <- W1 [128][512]
        int n = idx >> 7, k = idx & 127;
        Wt1[idx] = (f16)W1[k * 512 + n];
        return;
    }
    idx -= 512 * 128;
    if (idx < 1024 * 512) {              // Wt2 [1024][512] <- W2 [512][1024]
        int n = idx >> 9, k = idx & 511;
        Wt2[idx] = (f16)W2[k * 1024 + n];
        return;
    }
    idx -= 1024 * 512;
    if (idx < 512 * 1024) {              // Wt3 [512][1024] <- W3 [1024][512]
        int n = idx >> 10, k = idx & 1023;
        Wt3[idx] = (f16)W3[k * 512 + n];
        return;
    }
    idx -= 512 * 1024;
    if (idx < 128 * 512) {               // Wt4 [128][512] <- W4 [512][32], zero-padded
        int n = idx >> 9, k = idx & 511;
        Wt4[idx] = (n < 32) ? (f16)W4[k * 32 + n] : (f16)0.f;
        return;
    }
    idx -= 128 * 512;
    if (idx < NN * D_IN) {               // xh <- x (fp32 -> fp16)
        xh[idx] = (f16)x[idx];
        return;
    }
    idx -= NN * D_IN;
    if (idx < NN + 1) degi_flag[idx] = 0;   // degi[NN] + flag
}

// int64 edge_index => odd 32-bit words all zero (ids < 10000). One atomic/wave.
__global__ void detect_i64(const int* __restrict__ e, int* __restrict__ flag) {
    int i = blockIdx.x * blockDim.x + threadIdx.x;
    bool nz = (i < NE) && (e[2 * i + 1] != 0);
    if (__any(nz) && (threadIdx.x & 63) == 0) atomicOr(flag, 1);
}

__global__ void convert_count(const int* __restrict__ e, const int* __restrict__ flag,
                              int* __restrict__ srcA, int* __restrict__ dstA,
                              int* __restrict__ degi) {
    int i = blockIdx.x * blockDim.x + threadIdx.x;
    if (i >= NE) return;
    int s, d;
    if (*flag) { s = e[i];     d = e[NE + i]; }
    else       { s = e[2 * i]; d = e[2 * NE + 2 * i]; }
    srcA[i] = s; dstA[i] = d;
    atomicAdd(&degi[d], 1);
}

// Single-block scan via wave shuffles: degi -> rowptr (exclusive) + fill + dinv.
__global__ __launch_bounds__(1024) void scan_rowptr(
    const int* __restrict__ degi, int* __restrict__ rowptr,
    int* __restrict__ fill, float* __restrict__ dinv) {
    __shared__ int wsum[16];
    __shared__ int carry_s;
    int tid = threadIdx.x;
    int lane = tid & 63, wid = tid >> 6;
    if (tid == 0) carry_s = 0;
    for (int base = 0; base < NN; base += 1024) {
        int i = base + tid;
        int v = (i < NN) ? degi[i] : 0;
        if (i < NN) dinv[i] = rsqrtf((float)(v + 1));  // +1 self-loop
        // inclusive wave scan
        int xs = v;
#pragma unroll
        for (int off = 1; off < 64; off <<= 1) {
            int t = __shfl_up(xs, off, 64);
            if (lane >= off) xs += t;
        }
        if (lane == 63) wsum[wid] = xs;
        __syncthreads();                       // B1 (also covers carry_s update)
        if (tid < 16) {
            int y = wsum[tid];
#pragma unroll
            for (int off = 1; off < 16; off <<= 1) {
                int t = __shfl_up(y, off, 16);
                if (tid >= off) y += t;
            }
            wsum[tid] = y;
        }
        __syncthreads();                       // B2
        int woff = wid ? wsum[wid - 1] : 0;
        int incl = xs + woff + carry_s;
        if (i < NN) { rowptr[i] = incl - v; fill[i] = incl - v; }
        __syncthreads();                       // B3: all carry_s reads done
        if (tid == 1023) carry_s = incl;
    }
    if (tid == 1023) rowptr[NN] = carry_s;
}

__global__ void scatter_edges(const int* __restrict__ srcA, const int* __restrict__ dstA,
                              int* __restrict__ fill, int* __restrict__ col) {
    int i = blockIdx.x * blockDim.x + threadIdx.x;
    if (i >= NE) return;
    int p = atomicAdd(&fill[dstA[i]], 1);
    col[p] = srcA[i];
}

// ---------------------------------------------------------------------------
// Pull aggregation (fp16 in/out): 256-thread blocks, 4 nodes/block (1 wave ea).
// out[n,:] = dinv[n]^2*in[n,:] + sum_e dinv[n]*dinv[src]*in[src,:]
// MODE 0: plain   MODE 1: +bias, relu.  VEC in {2,8}, D = 64*VEC.
// ---------------------------------------------------------------------------
template <int VEC>
__device__ __forceinline__ void acc_row(const f16* p, float w, float (&a)[VEC]) {
    if constexpr (VEC == 8) {
        f16x8 t = *reinterpret_cast<const f16x8*>(p);
#pragma unroll
        for (int j = 0; j < 8; ++j) a[j] = fmaf(w, (float)t[j], a[j]);
    } else {
        f16x2 t = *reinterpret_cast<const f16x2*>(p);
        a[0] = fmaf(w, (float)t[0], a[0]);
        a[1] = fmaf(w, (float)t[1], a[1]);
    }
}

template <int VEC, int MODE>
__global__ __launch_bounds__(256) void agg_kernel(
    const f16* __restrict__ in, f16* __restrict__ out,
    const int* __restrict__ rowptr, const int* __restrict__ col,
    const float* __restrict__ dinv, const float* __restrict__ bias) {
    const int D = 64 * VEC;
    int n = blockIdx.x * 4 + (threadIdx.x >> 6);
    if (n >= NN) return;
    int lane = threadIdx.x & 63;
    int d0 = lane * VEC;
    float di = dinv[n];
    float acc[VEC];
#pragma unroll
    for (int v = 0; v < VEC; ++v) acc[v] = 0.f;
    acc_row<VEC>(in + (size_t)n * D + d0, di * di, acc);
    int e0 = rowptr[n], e1 = rowptr[n + 1];
#pragma unroll 2
    for (int e = e0; e < e1; ++e) {
        int s = col[e];
        acc_row<VEC>(in + (size_t)s * D + d0, di * dinv[s], acc);
    }
    f16 o[VEC];
#pragma unroll
    for (int v = 0; v < VEC; ++v) {
        float xv = acc[v];
        if (MODE >= 1) xv += bias[d0 + v];
        if (MODE == 1) xv = fmaxf(xv, 0.f);
        o[v] = (f16)xv;
    }
    if constexpr (VEC == 8)
        *reinterpret_cast<f16x8*>(out + (size_t)n * D + d0) = *reinterpret_cast<f16x8*>(o);
    else
        *reinterpret_cast<f16x2*>(out + (size_t)n * D + d0) = *reinterpret_cast<f16x2*>(o);
}

// ---------------------------------------------------------------------------
// fp16 MFMA GEMM: C[M,N] = A[M,K] @ Bt[N,K]^T, fp32 accumulate, fp16 out.
// 128x128 tile, BK=32, 256 threads = 4 waves (2x2), 64x64/wave,
// mfma_f32_16x16x32_f16 4x4 frags. M%128==0, N%128==0, K%32==0.
// LDS linear dest for global_load_lds; 16B-slot XOR swizzle on GLOBAL source
// and ds_read side (same involution, rule 21). XCD-bijective block swizzle
// (m204) over the linearized grid. MODE 0: plain  MODE 1: +bias, relu.
// ---------------------------------------------------------------------------
__device__ __forceinline__ void gload_lds16(const void* g, void* lds) {
    __builtin_amdgcn_global_load_lds(
        (const __attribute__((address_space(1))) void*)g,
        (__attribute__((address_space(3))) void*)lds, 16, 0, 0);
}

template <int MODE>
__global__ __launch_bounds__(256) void hgemm(
    const f16* __restrict__ A, const f16* __restrict__ Bt,
    const float* __restrict__ bias, f16* __restrict__ C, int K, int N) {
    __shared__ __align__(16) f16 As[128 * 32];
    __shared__ __align__(16) f16 Bs[128 * 32];
    const int tid = threadIdx.x;
    const int lane = tid & 63, w = tid >> 6;
    const int wm = w >> 1, wn = w & 1;

    // XCD-bijective swizzle (m204): contiguous chunks per XCD
    const int gx = gridDim.x;
    const int nwg = gx * gridDim.y;
    int lin = blockIdx.y * gx + blockIdx.x;
    {
        int q = nwg >> 3, r = nwg & 7;
        int xcd = lin & 7, j = lin >> 3;
        lin = (xcd < r ? xcd * (q + 1) : r * (q + 1) + (xcd - r) * q) + j;
    }
    const int bn = lin % gx, bm = lin / gx;

    f32x4 acc[4][4] = {};

    const int srow = tid >> 2;     // staging row (0..63), +64 for i=1
    const int sslot = tid & 3;     // 16B slot within 64B row

    for (int k0 = 0; k0 < K; k0 += 32) {
        if (k0) __syncthreads();
#pragma unroll
        for (int i = 0; i < 2; ++i) {
            int row = srow + i * 64;
            int g = sslot ^ ((row >> 1) & 3);          // inverse-swizzled source slot
            gload_lds16(A + (size_t)(bm * 128 + row) * K + k0 + g * 8,
                        (char*)As + w * 1024 + i * 4096);
            gload_lds16(Bt + (size_t)(bn * 128 + row) * K + k0 + g * 8,
                        (char*)Bs + w * 1024 + i * 4096);
        }
        __syncthreads();

        f16x8 af[4], bf[4];
        const int kg = lane >> 4;
#pragma unroll
        for (int m = 0; m < 4; ++m) {
            int row = wm * 64 + m * 16 + (lane & 15);
            int s = kg ^ ((row >> 1) & 3);
            af[m] = *reinterpret_cast<const f16x8*>((const char*)As + row * 64 + s * 16);
        }
#pragma unroll
        for (int n = 0; n < 4; ++n) {
            int row = wn * 64 + n * 16 + (lane & 15);
            int s = kg ^ ((row >> 1) & 3);
            bf[n] = *reinterpret_cast<const f16x8*>((const char*)Bs + row * 64 + s * 16);
        }
#pragma unroll
        for (int m = 0; m < 4; ++m)
#pragma unroll
            for (int n = 0; n < 4; ++n)
                acc[m][n] = __builtin_amdgcn_mfma_f32_16x16x32_f16(af[m], bf[n], acc[m][n], 0, 0, 0);
    }

    // epilogue: C row = (lane>>4)*4 + reg, col = lane&15 (m89-verified mapping)
#pragma unroll
    for (int n = 0; n < 4; ++n) {
        int colg = bn * 128 + wn * 64 + n * 16 + (lane & 15);
        float bv = (MODE == 1) ? bias[colg] : 0.f;
#pragma unroll
        for (int m = 0; m < 4; ++m) {
            int rbase = bm * 128 + wm * 64 + m * 16 + ((lane >> 4) << 2);
#pragma unroll
            for (int r = 0; r < 4; ++r) {
                float xv = acc[m][n][r];
                if (MODE == 1) { xv += bv; xv = fmaxf(xv, 0.f); }
                C[(size_t)(rbase + r) * N + colg] = (f16)xv;
            }
        }
    }
}

// ---------------------------------------------------------------------------
// Final: aggregate logits (D=32, stride 128) + bias + log_softmax, fused.
// 256-thread blocks, 8 nodes/block (2 per wave, 32 lanes each).
// ---------------------------------------------------------------------------
__global__ __launch_bounds__(256) void final_agg_softmax(
    const f16* __restrict__ in,     // [MPAD][128], cols 0..31 valid
    float* __restrict__ out,        // [NN][32]
    const int* __restrict__ rowptr, const int* __restrict__ col,
    const float* __restrict__ dinv, const float* __restrict__ b4) {
    int n = blockIdx.x * 8 + (threadIdx.x >> 5);
    int c = threadIdx.x & 31;
    if (n >= NN) return;
    float di = dinv[n];
    float acc = di * di * (float)in[(size_t)n * 128 + c];
    int e0 = rowptr[n], e1 = rowptr[n + 1];
    for (int e = e0; e < e1; ++e) {
        int s = col[e];
        acc = fmaf(di * dinv[s], (float)in[(size_t)s * 128 + c], acc);
    }
    float v = acc + b4[c];
    float mx = v;
#pragma unroll
    for (int o = 16; o; o >>= 1) mx = fmaxf(mx, __shfl_xor(mx, o, 32));
    float e = expf(v - mx);
    float s = e;
#pragma unroll
    for (int o = 16; o; o >>= 1) s += __shfl_xor(s, o, 32);
    out[(size_t)n * 32 + c] = v - mx - logf(s);
}

// ---------------------------------------------------------------------------

extern "C" void kernel_launch(void* const* d_in, const int* in_sizes, int n_in,
                              void* d_out, int out_size, void* d_ws, size_t ws_size,
                              hipStream_t stream) {
    const float* x  = (const float*)d_in[0];
    const int* eidx = (const int*)d_in[1];
    const float* W1 = (const float*)d_in[2]; const float* b1 = (const float*)d_in[3];
    const float* W2 = (const float*)d_in[4]; const float* b2 = (const float*)d_in[5];
    const float* W3 = (const float*)d_in[6]; const float* b3 = (const float*)d_in[7];
    const float* W4 = (const float*)d_in[8]; const float* b4 = (const float*)d_in[9];
    float* out = (float*)d_out;

    // workspace carve-up (~49 MB)
    f16* P1    = (f16*)d_ws;                           // [MPAD][<=1024]
    f16* P2    = P1 + (size_t)MPAD * 1024;             // [MPAD][<=1024]
    f16* xh    = P2 + (size_t)MPAD * 1024;             // [NN][128]
    f16* Wt1   = xh + (size_t)NN * 128;                // [512][128]
    f16* Wt2   = Wt1 + 512 * 128;                      // [1024][512]
    f16* Wt3   = Wt2 + 1024 * 512;                     // [512][1024]
    f16* Wt4   = Wt3 + 512 * 1024;                     // [128][512] (zero-padded)
    int* srcA  = (int*)(Wt4 + 128 * 512);              // NE
    int* dstA  = srcA + NE;
    int* colA  = dstA + NE;
    int* degi  = colA + NE;                            // NN, flag right after
    int* flag  = degi + NN;                            // 1
    int* rowptr = flag + 1;                            // NN+1
    int* fill  = rowptr + (NN + 1);                    // NN
    float* dinv = (float*)(fill + NN);                 // NN

    const int B256 = 256;
    int gE = (NE + B256 - 1) / B256;
    const int PREP_ELEMS = 512 * 128 + 1024 * 512 + 512 * 1024 + 128 * 512 + NN * D_IN + NN + 1;

    // --- preprocessing (5 dispatches) ---
    prep_all<<<(PREP_ELEMS + B256 - 1) / B256, B256, 0, stream>>>(
        W1, W2, W3, W4, x, Wt1, Wt2, Wt3, Wt4, xh, degi);
    detect_i64<<<gE, B256, 0, stream>>>(eidx, flag);
    convert_count<<<gE, B256, 0, stream>>>(eidx, flag, srcA, dstA, degi);
    scan_rowptr<<<1, 1024, 0, stream>>>(degi, rowptr, fill, dinv);
    scatter_edges<<<gE, B256, 0, stream>>>(srcA, dstA, fill, colA);

    // --- layer 1: aggregate xh (fp16, D=128), GEMM1 + bias + relu ---
    agg_kernel<2, 0><<<(NN + 3) / 4, B256, 0, stream>>>(xh, P1, rowptr, colA, dinv, nullptr);
    hgemm<1><<<dim3(D_H1 / 128, MPAD / 128), B256, 0, stream>>>(P1, Wt1, b1, P2, D_IN, D_H1);

    // --- layer 2: aggregate h1 (D=512), GEMM2 + bias + relu ---
    agg_kernel<8, 0><<<(NN + 3) / 4, B256, 0, stream>>>(P2, P1, rowptr, colA, dinv, nullptr);
    hgemm<1><<<dim3(D_H2 / 128, MPAD / 128), B256, 0, stream>>>(P1, Wt2, b2, P2, D_H1, D_H2);

    // --- layer 3: GEMM3 (plain), aggregate + bias + relu ---
    hgemm<0><<<dim3(D_H3 / 128, MPAD / 128), B256, 0, stream>>>(P2, Wt3, nullptr, P1, D_H2, D_H3);
    agg_kernel<8, 1><<<(NN + 3) / 4, B256, 0, stream>>>(P1, P2, rowptr, colA, dinv, b3);

    // --- layer 4: MFMA GEMM on zero-padded W4 (N=128), fused agg+softmax ---
    hgemm<0><<<dim3(1, MPAD / 128), B256, 0, stream>>>(P2, Wt4, nullptr, P1, D_H3, 128);
    final_agg_softmax<<<(NN + 7) / 8, B256, 0, stream>>>(P1, out, rowptr, colA, dinv, b4);
}

// Round 9
// 256.751 us; speedup vs baseline: 2.6104x; 1.1139x over previous
//
#include <hip/hip_runtime.h>
#include <math.h>

typedef _Float16 f16;
typedef f16 f16x8 __attribute__((ext_vector_type(8)));
typedef f16 f16x2 __attribute__((ext_vector_type(2)));
typedef float f32x4 __attribute__((ext_vector_type(4)));

constexpr int NN = 10000;      // nodes
constexpr int NE = 160000;     // edges (before self-loops)
constexpr int MPAD = 10112;    // 79 * 128, row padding for 128-tiles
constexpr int D_IN = 128, D_H1 = 512, D_H2 = 1024, D_H3 = 512, D_OUT = 32;

// ---------------------------------------------------------------------------
// Kernel 1: all one-shot prep — zero degi, convert weights (transposed fp16,
// K-contiguous), convert x to fp16. No inter-dependencies.
// ---------------------------------------------------------------------------
__global__ void prep_all(const float* __restrict__ W1, const float* __restrict__ W2,
                         const float* __restrict__ W3, const float* __restrict__ W4,
                         const float* __restrict__ x,
                         f16* __restrict__ Wt1, f16* __restrict__ Wt2,
                         f16* __restrict__ Wt3, f16* __restrict__ Wt4,
                         f16* __restrict__ xh, int* __restrict__ degi) {
    int idx = blockIdx.x * blockDim.x + threadIdx.x;
    if (idx < 512 * 128) {               // Wt1 [512][128] <- W1 [128][512]
        int n = idx >> 7, k = idx & 127;
        Wt1[idx] = (f16)W1[k * 512 + n];
        return;
    }
    idx -= 512 * 128;
    if (idx < 1024 * 512) {              // Wt2 [1024][512] <- W2 [512][1024]
        int n = idx >> 9, k = idx & 511;
        Wt2[idx] = (f16)W2[k * 1024 + n];
        return;
    }
    idx -= 1024 * 512;
    if (idx < 512 * 1024) {              // Wt3 [512][1024] <- W3 [1024][512]
        int n = idx >> 10, k = idx & 1023;
        Wt3[idx] = (f16)W3[k * 512 + n];
        return;
    }
    idx -= 512 * 1024;
    if (idx < 128 * 512) {               // Wt4 [128][512] <- W4 [512][32], zero-padded
        int n = idx >> 9, k = idx & 511;
        Wt4[idx] = (n < 32) ? (f16)W4[k * 32 + n] : (f16)0.f;
        return;
    }
    idx -= 128 * 512;
    if (idx < NN * D_IN) {               // xh <- x (fp32 -> fp16)
        xh[idx] = (f16)x[idx];
        return;
    }
    idx -= NN * D_IN;
    if (idx < NN) degi[idx] = 0;
}

// Convert edge_index (int64 or int32 layout, detected per-wave) -> src/dst,
// and count in-degrees. int64 layout => odd 32-bit words all zero (ids<10000);
// for int32 layout P(64 consecutive odd words all zero) ~ (1e-4)^64 ~ 0.
__global__ void convert_count(const int* __restrict__ e,
                              int* __restrict__ srcA, int* __restrict__ dstA,
                              int* __restrict__ degi) {
    int i = blockIdx.x * blockDim.x + threadIdx.x;
    bool nz = (i < NE) && (e[2 * i + 1] != 0);
    bool is32 = __any(nz);               // wave-uniform layout verdict
    if (i >= NE) return;
    int s, d;
    if (is32) { s = e[i];     d = e[NE + i]; }
    else      { s = e[2 * i]; d = e[2 * NE + 2 * i]; }
    srcA[i] = s; dstA[i] = d;
    atomicAdd(&degi[d], 1);
}

// Single-block scan via wave shuffles: degi -> rowptr (exclusive) + fill + dinv.
__global__ __launch_bounds__(1024) void scan_rowptr(
    const int* __restrict__ degi, int* __restrict__ rowptr,
    int* __restrict__ fill, float* __restrict__ dinv) {
    __shared__ int wsum[16];
    __shared__ int carry_s;
    int tid = threadIdx.x;
    int lane = tid & 63, wid = tid >> 6;
    if (tid == 0) carry_s = 0;
    for (int base = 0; base < NN; base += 1024) {
        int i = base + tid;
        int v = (i < NN) ? degi[i] : 0;
        if (i < NN) dinv[i] = rsqrtf((float)(v + 1));  // +1 self-loop
        int xs = v;
#pragma unroll
        for (int off = 1; off < 64; off <<= 1) {
            int t = __shfl_up(xs, off, 64);
            if (lane >= off) xs += t;
        }
        if (lane == 63) wsum[wid] = xs;
        __syncthreads();                       // B1 (also covers carry_s update)
        if (tid < 16) {
            int y = wsum[tid];
#pragma unroll
            for (int off = 1; off < 16; off <<= 1) {
                int t = __shfl_up(y, off, 16);
                if (tid >= off) y += t;
            }
            wsum[tid] = y;
        }
        __syncthreads();                       // B2
        int woff = wid ? wsum[wid - 1] : 0;
        int incl = xs + woff + carry_s;
        if (i < NN) { rowptr[i] = incl - v; fill[i] = incl - v; }
        __syncthreads();                       // B3: all carry_s reads done
        if (tid == 1023) carry_s = incl;
    }
    if (tid == 1023) rowptr[NN] = carry_s;
}

__global__ void scatter_edges(const int* __restrict__ srcA, const int* __restrict__ dstA,
                              int* __restrict__ fill, int* __restrict__ col) {
    int i = blockIdx.x * blockDim.x + threadIdx.x;
    if (i >= NE) return;
    int p = atomicAdd(&fill[dstA[i]], 1);
    col[p] = srcA[i];
}

// ---------------------------------------------------------------------------
// Pull aggregation (fp16 in/out): 256-thread blocks, 4 nodes/block (1 wave ea).
// out[n,:] = dinv[n]^2*in[n,:] + sum_e dinv[n]*dinv[src]*in[src,:]
// MODE 0: plain   MODE 1: +bias, relu.  VEC in {2,8}, D = 64*VEC.
// ---------------------------------------------------------------------------
template <int VEC>
__device__ __forceinline__ void acc_row(const f16* p, float w, float (&a)[VEC]) {
    if constexpr (VEC == 8) {
        f16x8 t = *reinterpret_cast<const f16x8*>(p);
#pragma unroll
        for (int j = 0; j < 8; ++j) a[j] = fmaf(w, (float)t[j], a[j]);
    } else {
        f16x2 t = *reinterpret_cast<const f16x2*>(p);
        a[0] = fmaf(w, (float)t[0], a[0]);
        a[1] = fmaf(w, (float)t[1], a[1]);
    }
}

template <int VEC, int MODE>
__global__ __launch_bounds__(256) void agg_kernel(
    const f16* __restrict__ in, f16* __restrict__ out,
    const int* __restrict__ rowptr, const int* __restrict__ col,
    const float* __restrict__ dinv, const float* __restrict__ bias) {
    const int D = 64 * VEC;
    int n = blockIdx.x * 4 + (threadIdx.x >> 6);
    if (n >= NN) return;
    int lane = threadIdx.x & 63;
    int d0 = lane * VEC;
    float di = dinv[n];
    float acc[VEC];
#pragma unroll
    for (int v = 0; v < VEC; ++v) acc[v] = 0.f;
    acc_row<VEC>(in + (size_t)n * D + d0, di * di, acc);
    int e0 = rowptr[n], e1 = rowptr[n + 1];
#pragma unroll 2
    for (int e = e0; e < e1; ++e) {
        int s = col[e];
        acc_row<VEC>(in + (size_t)s * D + d0, di * dinv[s], acc);
    }
    f16 o[VEC];
#pragma unroll
    for (int v = 0; v < VEC; ++v) {
        float xv = acc[v];
        if (MODE >= 1) xv += bias[d0 + v];
        if (MODE == 1) xv = fmaxf(xv, 0.f);
        o[v] = (f16)xv;
    }
    if constexpr (VEC == 8)
        *reinterpret_cast<f16x8*>(out + (size_t)n * D + d0) = *reinterpret_cast<f16x8*>(o);
    else
        *reinterpret_cast<f16x2*>(out + (size_t)n * D + d0) = *reinterpret_cast<f16x2*>(o);
}

// ---------------------------------------------------------------------------
// fp16 MFMA GEMM v2: C[M,N] = A[M,K] @ Bt[N,K]^T, fp32 accumulate, fp16 out.
// 128x128 tile, BK=64, double-buffered LDS, 2-phase prefetch pipeline
// (stage t+1 -> compute t -> one barrier/iter). 256 threads = 4 waves (2x2),
// 64x64/wave, mfma_f32_16x16x32_f16 4x4 frags, 2 k-steps per tile.
// M%128==0, N%128==0, K%64==0.
// LDS linear dest (global_load_lds); 16B-slot XOR swizzle (8 slots/row):
// source slot g = lin ^ (row&7), ds_read slot (kk*4+kg) ^ (row&7) — same
// involution both sides (rule 21); 2-way residual bank aliasing = free.
// XCD-bijective block swizzle (m204). MODE 0: plain  MODE 1: +bias, relu.
// ---------------------------------------------------------------------------
__device__ __forceinline__ void gload_lds16(const void* g, void* lds) {
    __builtin_amdgcn_global_load_lds(
        (const __attribute__((address_space(1))) void*)g,
        (__attribute__((address_space(3))) void*)lds, 16, 0, 0);
}

template <int MODE>
__global__ __launch_bounds__(256) void hgemm(
    const f16* __restrict__ A, const f16* __restrict__ Bt,
    const float* __restrict__ bias, f16* __restrict__ C, int K, int N) {
    __shared__ __align__(16) f16 As[2 * 128 * 64];   // 32 KB
    __shared__ __align__(16) f16 Bs[2 * 128 * 64];   // 32 KB
    const int tid = threadIdx.x;
    const int lane = tid & 63, w = tid >> 6;
    const int wm = w >> 1, wn = w & 1;

    // XCD-bijective swizzle (m204): contiguous chunks per XCD
    const int gx = gridDim.x;
    const int nwg = gx * gridDim.y;
    int lin = blockIdx.y * gx + blockIdx.x;
    {
        int q = nwg >> 3, r = nwg & 7;
        int xcd = lin & 7, j = lin >> 3;
        lin = (xcd < r ? xcd * (q + 1) : r * (q + 1) + (xcd - r) * q) + j;
    }
    const int bn = lin % gx, bm = lin / gx;

    f32x4 acc[4][4] = {};

    // Staging: thread t, chunk i (0..3) owns LDS bytes [t*16 + i*4096] of a
    // 16 KB buffer = row-major [128 rows][8 slots of 16B]:
    //   row = (t>>3) + i*32, linear slot = t&7.
    const int srow = tid >> 3;
    const int sslot = tid & 7;

    const int nt = K >> 6;                 // K/64 tiles

    // prologue: stage tile 0 into buffer 0
#pragma unroll
    for (int i = 0; i < 4; ++i) {
        int row = srow + i * 32;
        int g = sslot ^ (row & 7);
        gload_lds16(A + (size_t)(bm * 128 + row) * K + g * 8,
                    (char*)As + tid * 16 + i * 4096);
        gload_lds16(Bt + (size_t)(bn * 128 + row) * K + g * 8,
                    (char*)Bs + tid * 16 + i * 4096);
    }
    __syncthreads();

    int cur = 0;
    const int kg = lane >> 4;
    for (int t = 0; t < nt; ++t) {
        // stage next tile into the other buffer (overlaps with compute below)
        if (t + 1 < nt) {
            int k0 = (t + 1) << 6;
            int nb = (cur ^ 1) * 16384;
#pragma unroll
            for (int i = 0; i < 4; ++i) {
                int row = srow + i * 32;
                int g = sslot ^ (row & 7);
                gload_lds16(A + (size_t)(bm * 128 + row) * K + k0 + g * 8,
                            (char*)As + nb + tid * 16 + i * 4096);
                gload_lds16(Bt + (size_t)(bn * 128 + row) * K + k0 + g * 8,
                            (char*)Bs + nb + tid * 16 + i * 4096);
            }
        }
        // compute current buffer: 2 k-steps of 32
        int cb = cur * 16384;
#pragma unroll
        for (int kk = 0; kk < 2; ++kk) {
            f16x8 af[4], bf[4];
#pragma unroll
            for (int m = 0; m < 4; ++m) {
                int row = wm * 64 + m * 16 + (lane & 15);
                int s = (kk * 4 + kg) ^ (row & 7);
                af[m] = *reinterpret_cast<const f16x8*>((const char*)As + cb + row * 128 + s * 16);
            }
#pragma unroll
            for (int n = 0; n < 4; ++n) {
                int row = wn * 64 + n * 16 + (lane & 15);
                int s = (kk * 4 + kg) ^ (row & 7);
                bf[n] = *reinterpret_cast<const f16x8*>((const char*)Bs + cb + row * 128 + s * 16);
            }
#pragma unroll
            for (int m = 0; m < 4; ++m)
#pragma unroll
                for (int n = 0; n < 4; ++n)
                    acc[m][n] = __builtin_amdgcn_mfma_f32_16x16x32_f16(af[m], bf[n], acc[m][n], 0, 0, 0);
        }
        __syncthreads();       // drains vmcnt (next tile staged) + lgkm; guards buffer reuse
        cur ^= 1;
    }

    // epilogue: C row = (lane>>4)*4 + reg, col = lane&15 (m89-verified mapping)
#pragma unroll
    for (int n = 0; n < 4; ++n) {
        int colg = bn * 128 + wn * 64 + n * 16 + (lane & 15);
        float bv = (MODE == 1) ? bias[colg] : 0.f;
#pragma unroll
        for (int m = 0; m < 4; ++m) {
            int rbase = bm * 128 + wm * 64 + m * 16 + ((lane >> 4) << 2);
#pragma unroll
            for (int r = 0; r < 4; ++r) {
                float xv = acc[m][n][r];
                if (MODE == 1) { xv += bv; xv = fmaxf(xv, 0.f); }
                C[(size_t)(rbase + r) * N + colg] = (f16)xv;
            }
        }
    }
}

// ---------------------------------------------------------------------------
// Final: aggregate logits (D=32, stride 128) + bias + log_softmax, fused.
// 256-thread blocks, 8 nodes/block (2 per wave, 32 lanes each).
// ---------------------------------------------------------------------------
__global__ __launch_bounds__(256) void final_agg_softmax(
    const f16* __restrict__ in,     // [MPAD][128], cols 0..31 valid
    float* __restrict__ out,        // [NN][32]
    const int* __restrict__ rowptr, const int* __restrict__ col,
    const float* __restrict__ dinv, const float* __restrict__ b4) {
    int n = blockIdx.x * 8 + (threadIdx.x >> 5);
    int c = threadIdx.x & 31;
    if (n >= NN) return;
    float di = dinv[n];
    float acc = di * di * (float)in[(size_t)n * 128 + c];
    int e0 = rowptr[n], e1 = rowptr[n + 1];
    for (int e = e0; e < e1; ++e) {
        int s = col[e];
        acc = fmaf(di * dinv[s], (float)in[(size_t)s * 128 + c], acc);
    }
    float v = acc + b4[c];
    float mx = v;
#pragma unroll
    for (int o = 16; o; o >>= 1) mx = fmaxf(mx, __shfl_xor(mx, o, 32));
    float e = expf(v - mx);
    float s = e;
#pragma unroll
    for (int o = 16; o; o >>= 1) s += __shfl_xor(s, o, 32);
    out[(size_t)n * 32 + c] = v - mx - logf(s);
}

// ---------------------------------------------------------------------------

extern "C" void kernel_launch(void* const* d_in, const int* in_sizes, int n_in,
                              void* d_out, int out_size, void* d_ws, size_t ws_size,
                              hipStream_t stream) {
    const float* x  = (const float*)d_in[0];
    const int* eidx = (const int*)d_in[1];
    const float* W1 = (const float*)d_in[2]; const float* b1 = (const float*)d_in[3];
    const float* W2 = (const float*)d_in[4]; const float* b2 = (const float*)d_in[5];
    const float* W3 = (const float*)d_in[6]; const float* b3 = (const float*)d_in[7];
    const float* W4 = (const float*)d_in[8]; const float* b4 = (const float*)d_in[9];
    float* out = (float*)d_out;

    // workspace carve-up (~49 MB)
    f16* P1    = (f16*)d_ws;                           // [MPAD][<=1024]
    f16* P2    = P1 + (size_t)MPAD * 1024;             // [MPAD][<=1024]
    f16* xh    = P2 + (size_t)MPAD * 1024;             // [NN][128]
    f16* Wt1   = xh + (size_t)NN * 128;                // [512][128]
    f16* Wt2   = Wt1 + 512 * 128;                      // [1024][512]
    f16* Wt3   = Wt2 + 1024 * 512;                     // [512][1024]
    f16* Wt4   = Wt3 + 512 * 1024;                     // [128][512] (zero-padded)
    int* srcA  = (int*)(Wt4 + 128 * 512);              // NE
    int* dstA  = srcA + NE;
    int* colA  = dstA + NE;
    int* degi  = colA + NE;                            // NN
    int* rowptr = degi + NN;                           // NN+1
    int* fill  = rowptr + (NN + 1);                    // NN
    float* dinv = (float*)(fill + NN);                 // NN

    const int B256 = 256;
    int gE = (NE + B256 - 1) / B256;
    const int PREP_ELEMS = 512 * 128 + 1024 * 512 + 512 * 1024 + 128 * 512 + NN * D_IN + NN;

    // --- preprocessing (4 dispatches) ---
    prep_all<<<(PREP_ELEMS + B256 - 1) / B256, B256, 0, stream>>>(
        W1, W2, W3, W4, x, Wt1, Wt2, Wt3, Wt4, xh, degi);
    convert_count<<<gE, B256, 0, stream>>>(eidx, srcA, dstA, degi);
    scan_rowptr<<<1, 1024, 0, stream>>>(degi, rowptr, fill, dinv);
    scatter_edges<<<gE, B256, 0, stream>>>(srcA, dstA, fill, colA);

    // --- layer 1: aggregate xh (fp16, D=128), GEMM1 + bias + relu ---
    agg_kernel<2, 0><<<(NN + 3) / 4, B256, 0, stream>>>(xh, P1, rowptr, colA, dinv, nullptr);
    hgemm<1><<<dim3(D_H1 / 128, MPAD / 128), B256, 0, stream>>>(P1, Wt1, b1, P2, D_IN, D_H1);

    // --- layer 2: aggregate h1 (D=512), GEMM2 + bias + relu ---
    agg_kernel<8, 0><<<(NN + 3) / 4, B256, 0, stream>>>(P2, P1, rowptr, colA, dinv, nullptr);
    hgemm<1><<<dim3(D_H2 / 128, MPAD / 128), B256, 0, stream>>>(P1, Wt2, b2, P2, D_H1, D_H2);

    // --- layer 3: GEMM3 (plain), aggregate + bias + relu ---
    hgemm<0><<<dim3(D_H3 / 128, MPAD / 128), B256, 0, stream>>>(P2, Wt3, nullptr, P1, D_H2, D_H3);
    agg_kernel<8, 1><<<(NN + 3) / 4, B256, 0, stream>>>(P1, P2, rowptr, colA, dinv, b3);

    // --- layer 4: MFMA GEMM on zero-padded W4 (N=128), fused agg+softmax ---
    hgemm<0><<<dim3(1, MPAD / 128), B256, 0, stream>>>(P2, Wt4, nullptr, P1, D_H3, 128);
    final_agg_softmax<<<(NN + 7) / 8, B256, 0, stream>>>(P1, out, rowptr, colA, dinv, b4);
}